// Round 1
// 56.592 us; speedup vs baseline: 1.0175x; 1.0175x over previous
//
#include <hip/hip_runtime.h>
#include <math.h>

#define IMG_W 512
#define OW 113

__device__ __forceinline__ float max4f(float4 v) { return fmaxf(fmaxf(v.x, v.y), fmaxf(v.z, v.w)); }
__device__ __forceinline__ float min4f(float4 v) { return fminf(fminf(v.x, v.y), fminf(v.z, v.w)); }

// One block = one 8x8 patch of windows (grid 15x15). Builds a packed (max,min)
// tile pyramid for its 23x23-tile halo in LDS, piggybacks separable horizontal
// window sums (h4/h8/h16) into the pool phases, then each window needs only
// ~15 LDS reads in the final phase. 4 barriers total.
// 512 threads (8 waves) per block: grid is only 225 blocks (<256 CUs), so
// occupancy was 1 wave/SIMD at 256 threads — all memory/LDS latency exposed.
// 512 threads doubles waves/SIMD with zero extra global traffic.
__global__ __launch_bounds__(512) void fd_fused(const float* __restrict__ X,
                                                float* __restrict__ out) {
    const int bi = blockIdx.x / 15;
    const int bj = blockIdx.x - bi * 15;
    const int t  = threadIdx.x;

    __shared__ float2 tmm[23][24];          // (max,min) of 4x4 px tiles
    __shared__ float2 p8[22][24];           // 8x8 px pools
    __shared__ float2 p16[20][24];          // 16x16
    __shared__ float2 p32[16][24];          // 32x32
    __shared__ float df4[23][25], df8[22][25], df16[20][25], df32[16][25];
    __shared__ float h4[23][9], h8[22][9], h16[20][9];   // horizontal window sums

    // ---- stage: per-4x4-tile max/min for the 23x23 halo (529 items) ----
    for (int idx = t; idx < 23 * 23; idx += 512) {
        const int lr = idx / 23, lc = idx - lr * 23;
        const int gr = min(bi * 8 + lr, 127);   // clamped entries feed only guarded windows
        const int gc = min(bj * 8 + lc, 127);
        const float* p = X + (gr * 4) * IMG_W + gc * 4;
        float4 a = *(const float4*)(p);
        float4 b = *(const float4*)(p + IMG_W);
        float4 c = *(const float4*)(p + 2 * IMG_W);
        float4 d = *(const float4*)(p + 3 * IMG_W);
        float mx = fmaxf(fmaxf(max4f(a), max4f(b)), fmaxf(max4f(c), max4f(d)));
        float mn = fminf(fminf(min4f(a), min4f(b)), fminf(min4f(c), min4f(d)));
        tmm[lr][lc] = make_float2(mx, mn);
        df4[lr][lc] = mx - mn;
    }
    __syncthreads();

    // ---- P8 pool (22x22 = 484) + h4 horizontal sums (23x8 = 184) ----
    if (t < 22 * 22) {
        const int lr = t / 22, lc = t - lr * 22;
        float2 q00 = tmm[lr][lc],     q01 = tmm[lr][lc + 1];
        float2 q10 = tmm[lr + 1][lc], q11 = tmm[lr + 1][lc + 1];
        float x = fmaxf(fmaxf(q00.x, q01.x), fmaxf(q10.x, q11.x));
        float n = fminf(fminf(q00.y, q01.y), fminf(q10.y, q11.y));
        p8[lr][lc] = make_float2(x, n);
        df8[lr][lc] = x - n;
    }
    if (t < 23 * 8) {
        const int r = t >> 3, wj = t & 7;
        float s = 0.f;
        #pragma unroll
        for (int b = 0; b < 16; ++b) s += df4[r][wj + b];
        h4[r][wj] = s;
    }
    __syncthreads();

    // ---- P16 pool (20x20 = 400 on t<400) + h8 (22x8 = 176 on t in [400,576)... fits 512 via split) ----
    if (t < 20 * 20) {
        const int lr = t / 20, lc = t - lr * 20;
        float2 q00 = p8[lr][lc],     q01 = p8[lr][lc + 2];
        float2 q10 = p8[lr + 2][lc], q11 = p8[lr + 2][lc + 2];
        float x = fmaxf(fmaxf(q00.x, q01.x), fmaxf(q10.x, q11.x));
        float n = fminf(fminf(q00.y, q01.y), fminf(q10.y, q11.y));
        p16[lr][lc] = make_float2(x, n);
        df16[lr][lc] = x - n;
    }
    {   // h8 on threads [336, 512): disjoint from nothing harmful; 176 threads
        const int u = t - 336;
        if (u >= 0 && u < 22 * 8) {
            const int r = u >> 3, wj = u & 7;
            float s = 0.f;
            #pragma unroll
            for (int b = 0; b < 8; ++b) s += df8[r][wj + 2 * b];
            h8[r][wj] = s;
        }
    }
    __syncthreads();

    // ---- P32 pool (16x16 = 256 on t<256) + h16 (20x8 = 160 on t in [256,416)) ----
    if (t < 256) {
        const int lr = t >> 4, lc = t & 15;
        float2 q00 = p16[lr][lc],     q01 = p16[lr][lc + 4];
        float2 q10 = p16[lr + 4][lc], q11 = p16[lr + 4][lc + 4];
        float x = fmaxf(fmaxf(q00.x, q01.x), fmaxf(q10.x, q11.x));
        float n = fminf(fminf(q00.y, q01.y), fminf(q10.y, q11.y));
        p32[lr][lc] = make_float2(x, n);
        df32[lr][lc] = x - n;
    } else {
        const int u = t - 256;
        if (u < 20 * 8) {
            const int r = u >> 3, wj = u & 7;
            float s = 0.f;
            #pragma unroll
            for (int b = 0; b < 4; ++b) s += df16[r][wj + 4 * b];
            h16[r][wj] = s;
        }
    }
    __syncthreads();

    // ---- final: 4 threads per window (waves 0..3 only), vertical combine ----
    if (t < 256) {
        const int q  = t >> 2;        // window 0..63
        const int pp = t & 3;         // part 0..3
        const int wi = q >> 3, wj = q & 7;

        float d4 = h4[wi + 4 * pp][wj]     + h4[wi + 4 * pp + 1][wj]
                 + h4[wi + 4 * pp + 2][wj] + h4[wi + 4 * pp + 3][wj];
        float d8 = h8[wi + 4 * pp][wj] + h8[wi + 4 * pp + 2][wj];
        float d16 = h16[wi + 4 * pp][wj];
        float d32 = 0.f, d64 = 0.f;
        if (pp < 2) d32 = df32[wi + 8 * pp][wj] + df32[wi + 8 * pp][wj + 8];
        if (pp == 0) {
            float2 a0 = p32[wi][wj],     a1 = p32[wi][wj + 8];
            float2 a2 = p32[wi + 8][wj], a3 = p32[wi + 8][wj + 8];
            d64 = fmaxf(fmaxf(a0.x, a1.x), fmaxf(a2.x, a3.x))
                - fminf(fminf(a0.y, a1.y), fminf(a2.y, a3.y));
        }

        d4  += __shfl_down(d4,  2, 64);  d4  += __shfl_down(d4,  1, 64);
        d8  += __shfl_down(d8,  2, 64);  d8  += __shfl_down(d8,  1, 64);
        d16 += __shfl_down(d16, 2, 64);  d16 += __shfl_down(d16, 1, 64);
        d32 += __shfl_down(d32, 1, 64);  // p0 += p1 (p2/p3 are 0)

        if (pp == 0) {
            const int gwi = bi * 8 + wi;
            const int gwj = bj * 8 + wj;
            if (gwi < OW && gwj < OW) {
                // fd = -(sum_i log2(s_i) * log2(d_i)) / sum_i log2(s_i)^2
                // ln-based form's ln2 factors cancel: use native v_log_f32.
                const float num = 6.f * __log2f(d64) + 5.f * __log2f(d32)
                                + 4.f * __log2f(d16) + 3.f * __log2f(d8)
                                + 2.f * __log2f(d4);
                out[gwi * OW + gwj] = -num / 90.0f;
            }
        }
    }
}

extern "C" void kernel_launch(void* const* d_in, const int* in_sizes, int n_in,
                              void* d_out, int out_size, void* d_ws, size_t ws_size,
                              hipStream_t stream) {
    const float* X = (const float*)d_in[0];
    float* out = (float*)d_out;
    fd_fused<<<15 * 15, 512, 0, stream>>>(X, out);
}